// Round 1
// baseline (612.160 us; speedup 1.0000x reference)
//
#include <hip/hip_runtime.h>
#include <hip/hip_bf16.h>

typedef __attribute__((ext_vector_type(8))) short short8;
typedef __attribute__((ext_vector_type(4))) float floatx4;

__device__ __forceinline__ ushort f2bf(float x) {
    __hip_bfloat16 h = __float2bfloat16(x);
    return __builtin_bit_cast(ushort, h);
}
__device__ __forceinline__ float bf2f(ushort u) {
    __hip_bfloat16 h = __builtin_bit_cast(__hip_bfloat16, u);
    return __bfloat162float(h);
}

// async global -> LDS, 16 bytes per lane. LDS dest must be wave-uniform base;
// HW adds lane*16. [guide: global_load_lds width=16, m97]
__device__ __forceinline__ void gload_lds16(const ushort* g, ushort* l) {
    __builtin_amdgcn_global_load_lds(
        (const __attribute__((address_space(1))) unsigned int*)(const void*)g,
        (__attribute__((address_space(3))) unsigned int*)(void*)l,
        16, 0, 0);
}

// ---------------------------------------------------------------------------
// Weight transpose + fp32->bf16: W[K][N] -> WT[N][K]
// ---------------------------------------------------------------------------
__global__ void transpose_bf16(const float* __restrict__ W, ushort* __restrict__ WT,
                               int K, int N) {
    __shared__ float tile[32][33];
    int nb = blockIdx.x * 32, kb = blockIdx.y * 32;
    int tx = threadIdx.x, ty = threadIdx.y;
    #pragma unroll
    for (int j = ty; j < 32; j += 8)
        tile[j][tx] = W[(size_t)(kb + j) * N + nb + tx];
    __syncthreads();
    #pragma unroll
    for (int j = ty; j < 32; j += 8)
        WT[(size_t)(nb + j) * K + kb + tx] = f2bf(tile[tx][j]);
}

// ---------------------------------------------------------------------------
// h0 = concat([inp, hz], -1) packed to bf16 [32768][1024]
// ---------------------------------------------------------------------------
__global__ void pack_h0(const float* __restrict__ inp, const float* __restrict__ hz,
                        ushort* __restrict__ h0) {
    size_t i = (size_t)blockIdx.x * blockDim.x + threadIdx.x;
    int c = (int)(i & 1023);
    size_t row = i >> 10;
    float v = (c < 512) ? inp[row * 512 + c] : hz[row * 512 + (c - 512)];
    h0[i] = f2bf(v);
}

// ---------------------------------------------------------------------------
// 128x128-tile bf16 MFMA GEMM with fused epilogue.
// A  [M][1024] bf16 row-major, BT [NOUT][1024] bf16 (i.e. W transposed).
// MODE 0: out_bf = carry_f32(concat inp/hz) + 0.1*tanh(acc + bias)
// MODE 1: out_bf = carry_bf16            + 0.1*tanh(acc + bias)
// MODE 2: out_bf = relu(acc + bias)
// MODE 3: out_f32 = tanh(acc + bias)
// ---------------------------------------------------------------------------
template <int MODE, int NOUT>
__global__ __launch_bounds__(256, 2) void gemm_ep(
    const ushort* __restrict__ A, const ushort* __restrict__ BT,
    const float* __restrict__ bias,
    const float* __restrict__ carryA, const float* __restrict__ carryB,
    const ushort* __restrict__ carryBf,
    ushort* __restrict__ outB, float* __restrict__ outF) {
    constexpr int K = 1024;
    __shared__ ushort As[128 * 32];
    __shared__ ushort Bs[128 * 32];

    const int tid = threadIdx.x;
    const int wave = tid >> 6, lane = tid & 63;
    const int mBase = blockIdx.y * 128;
    const int nBase = blockIdx.x * 128;
    const int waveM = wave >> 1, waveN = wave & 1;

    // staging: 512 chunks of 16B per tile; wave w, issue i covers chunks
    // w*128 + i*64 + lane. chunk c -> row c>>2, k-offset (c&3)*8.
    const int c0 = wave * 128 + lane;
    const int c1 = c0 + 64;
    const ushort* ag0 = A + (size_t)(mBase + (c0 >> 2)) * K + (c0 & 3) * 8;
    const ushort* ag1 = A + (size_t)(mBase + (c1 >> 2)) * K + (c1 & 3) * 8;
    const ushort* bg0 = BT + (size_t)(nBase + (c0 >> 2)) * K + (c0 & 3) * 8;
    const ushort* bg1 = BT + (size_t)(nBase + (c1 >> 2)) * K + (c1 & 3) * 8;
    ushort* asD0 = As + (wave * 128) * 8;        // wave-uniform LDS bases
    ushort* asD1 = As + (wave * 128 + 64) * 8;
    ushort* bsD0 = Bs + (wave * 128) * 8;
    ushort* bsD1 = Bs + (wave * 128 + 64) * 8;

    floatx4 acc[4][4];
    #pragma unroll
    for (int i = 0; i < 4; i++)
        #pragma unroll
        for (int j = 0; j < 4; j++) acc[i][j] = (floatx4)(0.f);

    const int mrow = lane & 15;
    const int kq = (lane >> 4) * 8;

    for (int k0 = 0; k0 < K; k0 += 32) {
        gload_lds16(ag0 + k0, asD0);
        gload_lds16(ag1 + k0, asD1);
        gload_lds16(bg0 + k0, bsD0);
        gload_lds16(bg1 + k0, bsD1);
        __syncthreads();  // compiler emits vmcnt(0) drain before s_barrier

        short8 af[4], bfr[4];
        #pragma unroll
        for (int t = 0; t < 4; t++) {
            af[t]  = *(const short8*)(As + (waveM * 64 + t * 16 + mrow) * 32 + kq);
            bfr[t] = *(const short8*)(Bs + (waveN * 64 + t * 16 + mrow) * 32 + kq);
        }
        #pragma unroll
        for (int mt = 0; mt < 4; mt++)
            #pragma unroll
            for (int nt = 0; nt < 4; nt++)
                acc[mt][nt] = __builtin_amdgcn_mfma_f32_16x16x32_bf16(
                    af[mt], bfr[nt], acc[mt][nt], 0, 0, 0);
        __syncthreads();
    }

    // epilogue: C/D layout col=lane&15, row=(lane>>4)*4+reg  [m89/m91]
    const int col0 = nBase + waveN * 64 + (lane & 15);
    const int row0 = mBase + waveM * 64 + (lane >> 4) * 4;
    #pragma unroll
    for (int mt = 0; mt < 4; mt++) {
        #pragma unroll
        for (int nt = 0; nt < 4; nt++) {
            const int col = col0 + nt * 16;
            const float bv = bias[col];
            #pragma unroll
            for (int r = 0; r < 4; r++) {
                const int row = row0 + mt * 16 + r;
                const float z = acc[mt][nt][r] + bv;
                if (MODE == 0) {
                    float carry = (col < 512) ? carryA[(size_t)row * 512 + col]
                                              : carryB[(size_t)row * 512 + (col - 512)];
                    outB[(size_t)row * NOUT + col] = f2bf(carry + 0.1f * tanhf(z));
                } else if (MODE == 1) {
                    float carry = bf2f(carryBf[(size_t)row * 1024 + col]);
                    outB[(size_t)row * NOUT + col] = f2bf(carry + 0.1f * tanhf(z));
                } else if (MODE == 2) {
                    outB[(size_t)row * NOUT + col] = f2bf(fmaxf(z, 0.f));
                } else {
                    outF[(size_t)row * NOUT + col] = tanhf(z);
                }
            }
        }
    }
}

extern "C" void kernel_launch(void* const* d_in, const int* in_sizes, int n_in,
                              void* d_out, int out_size, void* d_ws, size_t ws_size,
                              hipStream_t stream) {
    const float* inp = (const float*)d_in[0];  // [32,1024,512]
    const float* hz  = (const float*)d_in[1];  // [32,1024,512]
    const float* Wf  = (const float*)d_in[2];  // [1024,1024]
    const float* bf_ = (const float*)d_in[3];  // [1024]
    const float* W1  = (const float*)d_in[4];  // [1024,1024]
    const float* b1  = (const float*)d_in[5];  // [1024]
    const float* W2  = (const float*)d_in[6];  // [1024,512]
    const float* b2  = (const float*)d_in[7];  // [512]
    float* out = (float*)d_out;                // [32,1024,512] fp32

    char* ws = (char*)d_ws;
    ushort* WfT  = (ushort*)(ws);                                  // 2 MB
    ushort* W1T  = (ushort*)(ws + (size_t)(2 << 20));              // 2 MB
    ushort* W2T  = (ushort*)(ws + (size_t)(4 << 20));              // 1 MB
    ushort* bufA = (ushort*)(ws + (size_t)(8 << 20));              // 64 MB
    ushort* bufB = (ushort*)(ws + (size_t)(8 << 20) + ((size_t)64 << 20));  // 64 MB

    // weight prep
    transpose_bf16<<<dim3(32, 32), dim3(32, 8), 0, stream>>>(Wf, WfT, 1024, 1024);
    transpose_bf16<<<dim3(32, 32), dim3(32, 8), 0, stream>>>(W1, W1T, 1024, 1024);
    transpose_bf16<<<dim3(16, 32), dim3(32, 8), 0, stream>>>(W2, W2T, 1024, 512);

    // h0 = bf16(concat(inp, hz))
    pack_h0<<<(32768 * 1024) / 256, 256, 0, stream>>>(inp, hz, bufA);

    // h1 = h0 + 0.1*tanh(h0@Wf + bf)   (carry read exact fp32 from inp/hz)
    gemm_ep<0, 1024><<<dim3(8, 256), 256, 0, stream>>>(bufA, WfT, bf_, inp, hz,
                                                       nullptr, bufB, nullptr);
    // h2 = h1 + 0.1*tanh(h1@Wf + bf)
    gemm_ep<1, 1024><<<dim3(8, 256), 256, 0, stream>>>(bufB, WfT, bf_, nullptr, nullptr,
                                                       bufB, bufA, nullptr);
    // g = relu(h2@W1 + b1)
    gemm_ep<2, 1024><<<dim3(8, 256), 256, 0, stream>>>(bufA, W1T, b1, nullptr, nullptr,
                                                       nullptr, bufB, nullptr);
    // out = tanh(g@W2 + b2)
    gemm_ep<3, 512><<<dim3(4, 256), 256, 0, stream>>>(bufB, W2T, b2, nullptr, nullptr,
                                                      nullptr, nullptr, out);
}

// Round 2
// 484.952 us; speedup vs baseline: 1.2623x; 1.2623x over previous
//
#include <hip/hip_runtime.h>
#include <hip/hip_bf16.h>

typedef __attribute__((ext_vector_type(8))) short short8;
typedef __attribute__((ext_vector_type(4))) float floatx4;

__device__ __forceinline__ ushort f2bf(float x) {
    __hip_bfloat16 h = __float2bfloat16(x);
    return __builtin_bit_cast(ushort, h);
}
__device__ __forceinline__ float bf2f(ushort u) {
    __hip_bfloat16 h = __builtin_bit_cast(__hip_bfloat16, u);
    return __bfloat162float(h);
}

// fast tanh: 1 - 2/(e^{2z}+1); v_exp + v_rcp, ~1e-6 abs err — fine for bf16-scale tol
__device__ __forceinline__ float fast_tanh(float z) {
    float e = __expf(2.0f * z);
    return 1.0f - 2.0f * __builtin_amdgcn_rcpf(e + 1.0f);
}

// async global -> LDS, 16 bytes per lane. LDS dest is wave-uniform base + lane*16;
// per-lane GLOBAL source is arbitrary (we exploit this for the bank swizzle).
__device__ __forceinline__ void gload_lds16(const ushort* g, ushort* l) {
    __builtin_amdgcn_global_load_lds(
        (const __attribute__((address_space(1))) unsigned int*)(const void*)g,
        (__attribute__((address_space(3))) unsigned int*)(void*)l,
        16, 0, 0);
}

// ---------------------------------------------------------------------------
// Weight transpose + fp32->bf16: W[K][N] -> WT[N][K]
// ---------------------------------------------------------------------------
__global__ void transpose_bf16(const float* __restrict__ W, ushort* __restrict__ WT,
                               int K, int N) {
    __shared__ float tile[32][33];
    int nb = blockIdx.x * 32, kb = blockIdx.y * 32;
    int tx = threadIdx.x, ty = threadIdx.y;
    #pragma unroll
    for (int j = ty; j < 32; j += 8)
        tile[j][tx] = W[(size_t)(kb + j) * N + nb + tx];
    __syncthreads();
    #pragma unroll
    for (int j = ty; j < 32; j += 8)
        WT[(size_t)(nb + j) * K + kb + tx] = f2bf(tile[tx][j]);
}

// ---------------------------------------------------------------------------
// h0 = concat([inp, hz], -1) packed to bf16 [32768][1024], float4-vectorized.
// blockIdx.y: 0 -> inp (cols 0..511), 1 -> hz (cols 512..1023)
// ---------------------------------------------------------------------------
__global__ void pack_h0(const float* __restrict__ inp, const float* __restrict__ hz,
                        ushort* __restrict__ h0) {
    const float* src = blockIdx.y ? hz : inp;
    size_t i = ((size_t)blockIdx.x * blockDim.x + threadIdx.x) * 4;  // over 32768*512
    size_t row = i >> 9;
    int col = (int)(i & 511);
    float4 v = *(const float4*)(src + i);
    ushort4 o;
    o.x = f2bf(v.x); o.y = f2bf(v.y); o.z = f2bf(v.z); o.w = f2bf(v.w);
    *(ushort4*)(h0 + row * 1024 + blockIdx.y * 512 + col) = o;
}

// ---------------------------------------------------------------------------
// 128x128-tile bf16 MFMA GEMM with fused epilogue.
// A  [M][1024] bf16 row-major, BT [NOUT][1024] bf16 (W transposed).
// MODE 1: out_bf = bf2f(A[row][col]) + 0.1*tanh(acc + bias)   (euler step)
// MODE 2: out_bf = relu(acc + bias)
// MODE 3: out_f32 = tanh(acc + bias)
// Grid: 1-D, NX*256 blocks. XCD swizzle: xcd=id&7 owns M-tiles [xcd*32, xcd*32+32),
// N-tiles iterate innermost so same-A blocks are temporally adjacent on one XCD.
// ---------------------------------------------------------------------------
template <int MODE, int NOUT, int NX>
__global__ __launch_bounds__(256, 2) void gemm_ep(
    const ushort* __restrict__ A, const ushort* __restrict__ BT,
    const float* __restrict__ bias,
    ushort* __restrict__ outB, float* __restrict__ outF) {
    constexpr int K = 1024;
    __shared__ ushort As[128 * 32];
    __shared__ ushort Bs[128 * 32];

    const int tid = threadIdx.x;
    const int wave = tid >> 6, lane = tid & 63;

    const int id = blockIdx.x;
    const int nTile = (id >> 3) % NX;
    const int mTile = (id & 7) * 32 + (id >> 3) / NX;
    const int mBase = mTile * 128;
    const int nBase = nTile * 128;
    const int waveM = wave >> 1, waveN = wave & 1;

    // Staging with XOR bank swizzle. Physical 16B slot c (LDS addr c*16) holds
    // logical (row r=c>>2, quad q=(c&3)^((r>>1)&3)). global_load_lds writes
    // base+lane*16; the per-lane global source encodes the swizzle.
    const int c0 = wave * 128 + lane;          // c1 = c0+64: r+16, same (r>>1)&3 -> same q
    const int r0 = c0 >> 2;
    const int q0 = (c0 & 3) ^ ((r0 >> 1) & 3);
    const ushort* ag0 = A + (size_t)(mBase + r0) * K + q0 * 8;
    const ushort* ag1 = A + (size_t)(mBase + r0 + 16) * K + q0 * 8;
    const ushort* bg0 = BT + (size_t)(nBase + r0) * K + q0 * 8;
    const ushort* bg1 = BT + (size_t)(nBase + r0 + 16) * K + q0 * 8;
    ushort* asD0 = As + (wave * 128) * 8;      // wave-uniform LDS bases
    ushort* asD1 = As + (wave * 128 + 64) * 8;
    ushort* bsD0 = Bs + (wave * 128) * 8;
    ushort* bsD1 = Bs + (wave * 128 + 64) * 8;

    floatx4 acc[4][4];
    #pragma unroll
    for (int i = 0; i < 4; i++)
        #pragma unroll
        for (int j = 0; j < 4; j++) acc[i][j] = (floatx4)(0.f);

    const int mrow = lane & 15;
    const int g = lane >> 4;                   // logical k-quad wanted
    const int pq = g ^ ((mrow >> 1) & 3);      // physical quad (invariant in t: t*16>>1 ≡ 0 mod 4)
    const int kqOff = pq * 8;

    for (int k0 = 0; k0 < K; k0 += 32) {
        gload_lds16(ag0 + k0, asD0);
        gload_lds16(ag1 + k0, asD1);
        gload_lds16(bg0 + k0, bsD0);
        gload_lds16(bg1 + k0, bsD1);
        __syncthreads();

        short8 af[4], bfr[4];
        #pragma unroll
        for (int t = 0; t < 4; t++) {
            af[t]  = *(const short8*)(As + (waveM * 64 + t * 16 + mrow) * 32 + kqOff);
            bfr[t] = *(const short8*)(Bs + (waveN * 64 + t * 16 + mrow) * 32 + kqOff);
        }
        #pragma unroll
        for (int mt = 0; mt < 4; mt++)
            #pragma unroll
            for (int nt = 0; nt < 4; nt++)
                acc[mt][nt] = __builtin_amdgcn_mfma_f32_16x16x32_bf16(
                    af[mt], bfr[nt], acc[mt][nt], 0, 0, 0);
        __syncthreads();
    }

    // epilogue: C/D layout col=lane&15, row=(lane>>4)*4+reg  [m89/m91]
    const int col0 = nBase + waveN * 64 + (lane & 15);
    const int row0 = mBase + waveM * 64 + (lane >> 4) * 4;
    #pragma unroll
    for (int mt = 0; mt < 4; mt++) {
        #pragma unroll
        for (int nt = 0; nt < 4; nt++) {
            const int col = col0 + nt * 16;
            const float bv = bias[col];
            #pragma unroll
            for (int r = 0; r < 4; r++) {
                const int row = row0 + mt * 16 + r;
                const float z = acc[mt][nt][r] + bv;
                if (MODE == 1) {
                    float carry = bf2f(A[(size_t)row * K + col]);
                    outB[(size_t)row * NOUT + col] = f2bf(carry + 0.1f * fast_tanh(z));
                } else if (MODE == 2) {
                    outB[(size_t)row * NOUT + col] = f2bf(fmaxf(z, 0.f));
                } else {
                    outF[(size_t)row * NOUT + col] = fast_tanh(z);
                }
            }
        }
    }
}

extern "C" void kernel_launch(void* const* d_in, const int* in_sizes, int n_in,
                              void* d_out, int out_size, void* d_ws, size_t ws_size,
                              hipStream_t stream) {
    const float* inp = (const float*)d_in[0];  // [32,1024,512]
    const float* hz  = (const float*)d_in[1];  // [32,1024,512]
    const float* Wf  = (const float*)d_in[2];  // [1024,1024]
    const float* bf_ = (const float*)d_in[3];  // [1024]
    const float* W1  = (const float*)d_in[4];  // [1024,1024]
    const float* b1  = (const float*)d_in[5];  // [1024]
    const float* W2  = (const float*)d_in[6];  // [1024,512]
    const float* b2  = (const float*)d_in[7];  // [512]
    float* out = (float*)d_out;                // [32,1024,512] fp32

    char* ws = (char*)d_ws;
    ushort* WfT  = (ushort*)(ws);                                  // 2 MB
    ushort* W1T  = (ushort*)(ws + (size_t)(2 << 20));              // 2 MB
    ushort* W2T  = (ushort*)(ws + (size_t)(4 << 20));              // 1 MB
    ushort* bufA = (ushort*)(ws + (size_t)(8 << 20));              // 64 MB
    ushort* bufB = (ushort*)(ws + (size_t)(8 << 20) + ((size_t)64 << 20));  // 64 MB

    // weight prep
    transpose_bf16<<<dim3(32, 32), dim3(32, 8), 0, stream>>>(Wf, WfT, 1024, 1024);
    transpose_bf16<<<dim3(32, 32), dim3(32, 8), 0, stream>>>(W1, W1T, 1024, 1024);
    transpose_bf16<<<dim3(16, 32), dim3(32, 8), 0, stream>>>(W2, W2T, 1024, 512);

    // h0 = bf16(concat(inp, hz)), float4-vectorized
    pack_h0<<<dim3((32768 * 512 / 4) / 256, 2), 256, 0, stream>>>(inp, hz, bufA);

    // h1 = h0 + 0.1*tanh(h0@Wf + bf)
    gemm_ep<1, 1024, 8><<<8 * 256, 256, 0, stream>>>(bufA, WfT, bf_, bufB, nullptr);
    // h2 = h1 + 0.1*tanh(h1@Wf + bf)
    gemm_ep<1, 1024, 8><<<8 * 256, 256, 0, stream>>>(bufB, WfT, bf_, bufA, nullptr);
    // g = relu(h2@W1 + b1)
    gemm_ep<2, 1024, 8><<<8 * 256, 256, 0, stream>>>(bufA, W1T, b1, bufB, nullptr);
    // out = tanh(g@W2 + b2)
    gemm_ep<3, 512, 4><<<4 * 256, 256, 0, stream>>>(bufB, W2T, b2, nullptr, out);
}

// Round 3
// 456.756 us; speedup vs baseline: 1.3402x; 1.0617x over previous
//
#include <hip/hip_runtime.h>
#include <hip/hip_bf16.h>

typedef __attribute__((ext_vector_type(8))) short short8;
typedef __attribute__((ext_vector_type(4))) float floatx4;

__device__ __forceinline__ ushort f2bf(float x) {
    __hip_bfloat16 h = __float2bfloat16(x);
    return __builtin_bit_cast(ushort, h);
}
__device__ __forceinline__ float bf2f(ushort u) {
    __hip_bfloat16 h = __builtin_bit_cast(__hip_bfloat16, u);
    return __bfloat162float(h);
}

// fast tanh: 1 - 2/(e^{2z}+1); v_exp + v_rcp, ~1e-6 abs err
__device__ __forceinline__ float fast_tanh(float z) {
    float e = __expf(2.0f * z);
    return 1.0f - 2.0f * __builtin_amdgcn_rcpf(e + 1.0f);
}

// async global -> LDS, 16 bytes per lane. LDS dest is wave-uniform base + lane*16;
// per-lane GLOBAL source is arbitrary (exploited for the XOR bank swizzle).
__device__ __forceinline__ void gload_lds16(const ushort* g, ushort* l) {
    __builtin_amdgcn_global_load_lds(
        (const __attribute__((address_space(1))) unsigned int*)(const void*)g,
        (__attribute__((address_space(3))) unsigned int*)(void*)l,
        16, 0, 0);
}

// ---------------------------------------------------------------------------
// Fused prep (one dispatch): h0 pack + all three weight transposes.
//   bid in [0,16384):       pack inp  -> h0 cols [0,512)
//   bid in [16384,32768):   pack hz   -> h0 cols [512,1024)
//   bid in [32768,33792):   Wf  [1024][1024] -> WfT
//   bid in [33792,34816):   W1  [1024][1024] -> W1T
//   bid in [34816,35328):   W2  [1024][512]  -> W2T
// ---------------------------------------------------------------------------
__global__ void prep(const float* __restrict__ inp, const float* __restrict__ hz,
                     const float* __restrict__ Wf, const float* __restrict__ W1,
                     const float* __restrict__ W2,
                     ushort* __restrict__ h0, ushort* __restrict__ WfT,
                     ushort* __restrict__ W1T, ushort* __restrict__ W2T) {
    int bid = blockIdx.x;
    int tid = threadIdx.x;
    __shared__ float tile[32][33];
    if (bid < 32768) {
        const float* src = (bid < 16384) ? inp : hz;
        int half = (bid < 16384) ? 0 : 1;
        int b = bid - half * 16384;
        size_t i = ((size_t)b * 256 + tid) * 4;   // over 32768*512 floats
        size_t row = i >> 9;
        int col = (int)(i & 511);
        float4 v = *(const float4*)(src + i);
        ushort4 o = make_ushort4(f2bf(v.x), f2bf(v.y), f2bf(v.z), f2bf(v.w));
        *(ushort4*)(h0 + row * 1024 + half * 512 + col) = o;
    } else {
        int t = bid - 32768;
        const float* W;
        ushort* WT;
        int K = 1024, N = 1024;
        if (t < 1024)      { W = Wf; WT = WfT; }
        else if (t < 2048) { W = W1; WT = W1T; t -= 1024; }
        else               { W = W2; WT = W2T; t -= 2048; N = 512; }
        int tx = tid & 31, ty = tid >> 5;
        int nb = (t % (N / 32)) * 32, kb = (t / (N / 32)) * 32;
        #pragma unroll
        for (int j = ty; j < 32; j += 8)
            tile[j][tx] = W[(size_t)(kb + j) * N + nb + tx];
        __syncthreads();
        #pragma unroll
        for (int j = ty; j < 32; j += 8)
            WT[(size_t)(nb + j) * K + kb + tx] = f2bf(tile[tx][j]);
    }
}

// ---------------------------------------------------------------------------
// 128(M)x256(N)-tile bf16 MFMA GEMM, 512 threads / 8 waves, fused epilogue.
// A [M][1024] bf16 row-major, BT [NOUT][1024] bf16 (W transposed).
// MODE 1: out_bf = bf2f(A[row][col]) + 0.1*tanh(acc + bias)   (euler step)
// MODE 2: out_bf = relu(acc + bias)
// MODE 3: out_f32 = tanh(acc + bias)
// Grid 1-D: xcd=id&7 owns M-tiles [xcd*32, xcd*32+32); N-tiles innermost.
// ---------------------------------------------------------------------------
template <int MODE, int NOUT, int NX>
__global__ __launch_bounds__(512, 4) void gemm_ep(
    const ushort* __restrict__ A, const ushort* __restrict__ BT,
    const float* __restrict__ bias,
    ushort* __restrict__ outB, float* __restrict__ outF) {
    constexpr int K = 1024;
    __shared__ ushort As[128 * 32];   //  8 KB
    __shared__ ushort Bs[256 * 32];   // 16 KB

    const int tid = threadIdx.x;
    const int wave = tid >> 6, lane = tid & 63;

    const int id = blockIdx.x;
    const int inner = id >> 3;
    const int nTile = inner % NX;
    const int mTile = (id & 7) * 32 + inner / NX;
    const int mBase = mTile * 128;
    const int nBase = nTile * 256;
    const int waveM = wave >> 2;      // 0..1  (64-row band)
    const int waveN = wave & 3;       // 0..3  (64-col band)

    // Staging with XOR bank swizzle: physical 16B slot c holds logical
    // (row r=c>>2, quad q=(c&3)^((r>>1)&3)). global_load_lds dest is
    // wave-uniform base + lane*16; the per-lane global source encodes the swizzle.
    // A: 512 chunks, 1 per lane. B: 1024 chunks, 2 per lane (+128 rows: same q).
    const int ca = wave * 64 + lane;
    const int ra = ca >> 2;
    const int qa = (ca & 3) ^ ((ra >> 1) & 3);
    const ushort* agA = A + (size_t)(mBase + ra) * K + qa * 8;
    const ushort* bg0 = BT + (size_t)(nBase + ra) * K + qa * 8;
    const ushort* bg1 = BT + (size_t)(nBase + ra + 128) * K + qa * 8;
    ushort* asD  = As + (size_t)(wave * 64) * 8;
    ushort* bsD0 = Bs + (size_t)(wave * 64) * 8;
    ushort* bsD1 = Bs + (size_t)(wave * 64 + 512) * 8;

    floatx4 acc[4][4];
    #pragma unroll
    for (int i = 0; i < 4; i++)
        #pragma unroll
        for (int j = 0; j < 4; j++) acc[i][j] = (floatx4)(0.f);

    const int mrow = lane & 15;
    const int g = lane >> 4;                  // logical k-quad
    const int pq = g ^ ((mrow >> 1) & 3);     // physical quad (t*16 doesn't affect it)
    const int kqOff = pq * 8;

    for (int k0 = 0; k0 < K; k0 += 32) {
        gload_lds16(agA + k0, asD);
        gload_lds16(bg0 + k0, bsD0);
        gload_lds16(bg1 + k0, bsD1);
        __syncthreads();

        short8 af[4], bfr[4];
        #pragma unroll
        for (int t = 0; t < 4; t++) {
            af[t]  = *(const short8*)(As + (waveM * 64 + t * 16 + mrow) * 32 + kqOff);
            bfr[t] = *(const short8*)(Bs + (waveN * 64 + t * 16 + mrow) * 32 + kqOff);
        }
        #pragma unroll
        for (int mt = 0; mt < 4; mt++)
            #pragma unroll
            for (int nt = 0; nt < 4; nt++)
                acc[mt][nt] = __builtin_amdgcn_mfma_f32_16x16x32_bf16(
                    af[mt], bfr[nt], acc[mt][nt], 0, 0, 0);
        __syncthreads();
    }

    // epilogue: C/D layout col=lane&15, row=(lane>>4)*4+reg  [m89/m91]
    const int col0 = nBase + waveN * 64 + (lane & 15);
    const int row0 = mBase + waveM * 64 + (lane >> 4) * 4;
    #pragma unroll
    for (int mt = 0; mt < 4; mt++) {
        #pragma unroll
        for (int nt = 0; nt < 4; nt++) {
            const int col = col0 + nt * 16;
            const float bv = bias[col];
            #pragma unroll
            for (int r = 0; r < 4; r++) {
                const int row = row0 + mt * 16 + r;
                const float z = acc[mt][nt][r] + bv;
                if (MODE == 1) {
                    float carry = bf2f(A[(size_t)row * K + col]);
                    outB[(size_t)row * NOUT + col] = f2bf(carry + 0.1f * fast_tanh(z));
                } else if (MODE == 2) {
                    outB[(size_t)row * NOUT + col] = f2bf(fmaxf(z, 0.f));
                } else {
                    outF[(size_t)row * NOUT + col] = fast_tanh(z);
                }
            }
        }
    }
}

extern "C" void kernel_launch(void* const* d_in, const int* in_sizes, int n_in,
                              void* d_out, int out_size, void* d_ws, size_t ws_size,
                              hipStream_t stream) {
    const float* inp = (const float*)d_in[0];  // [32,1024,512]
    const float* hz  = (const float*)d_in[1];  // [32,1024,512]
    const float* Wf  = (const float*)d_in[2];  // [1024,1024]
    const float* bf_ = (const float*)d_in[3];  // [1024]
    const float* W1  = (const float*)d_in[4];  // [1024,1024]
    const float* b1  = (const float*)d_in[5];  // [1024]
    const float* W2  = (const float*)d_in[6];  // [1024,512]
    const float* b2  = (const float*)d_in[7];  // [512]
    float* out = (float*)d_out;                // [32,1024,512] fp32

    char* ws = (char*)d_ws;
    ushort* WfT  = (ushort*)(ws);                                  // 2 MB
    ushort* W1T  = (ushort*)(ws + (size_t)(2 << 20));              // 2 MB
    ushort* W2T  = (ushort*)(ws + (size_t)(4 << 20));              // 1 MB
    ushort* bufA = (ushort*)(ws + (size_t)(8 << 20));              // 64 MB
    ushort* bufB = (ushort*)(ws + (size_t)(8 << 20) + ((size_t)64 << 20));  // 64 MB

    // fused prep: h0 pack + 3 weight transposes, one dispatch
    prep<<<35328, 256, 0, stream>>>(inp, hz, Wf, W1, W2, bufA, WfT, W1T, W2T);

    // h1 = h0 + 0.1*tanh(h0@Wf + bf)
    gemm_ep<1, 1024, 4><<<1024, 512, 0, stream>>>(bufA, WfT, bf_, bufB, nullptr);
    // h2 = h1 + 0.1*tanh(h1@Wf + bf)
    gemm_ep<1, 1024, 4><<<1024, 512, 0, stream>>>(bufB, WfT, bf_, bufA, nullptr);
    // g = relu(h2@W1 + b1)
    gemm_ep<2, 1024, 4><<<1024, 512, 0, stream>>>(bufA, W1T, b1, bufB, nullptr);
    // out = tanh(g@W2 + b2)
    gemm_ep<3, 512, 2><<<512, 512, 0, stream>>>(bufB, W2T, b2, nullptr, out);
}